// Round 1
// baseline (269.329 us; speedup 1.0000x reference)
//
#include <hip/hip_runtime.h>
#include <hip/hip_bf16.h>
#include <stdint.h>

#define DIM   512
#define INNER 512
#define HEADS 8
#define DH    64
#define B_    4
#define N_    2048
#define ROWS  (B_*N_)     // 8192
#define QKVN  (3*INNER)   // 1536

typedef __attribute__((ext_vector_type(8))) short bf8_t;  // 8 bf16 (4 VGPRs)
typedef __attribute__((ext_vector_type(4))) float f4_t;   // MFMA C/D

__device__ __forceinline__ unsigned short f2bf(float f){
  union { float f; unsigned u; } x; x.f = f;
  unsigned u = x.u;
  return (unsigned short)((u + 0x7fffu + ((u >> 16) & 1u)) >> 16);  // RTNE
}
__device__ __forceinline__ float bf2f(unsigned short h){
  union { unsigned u; float f; } x; x.u = ((unsigned)h) << 16; return x.f;
}

// ---------------- LayerNorm: fp32 [8192,512] -> bf16 xn ----------------
__global__ __launch_bounds__(128)
void ln_kernel(const float* __restrict__ x, const float* __restrict__ g,
               const float* __restrict__ b, unsigned short* __restrict__ xn)
{
  const int row = blockIdx.x;
  const int t = threadIdx.x;
  const float4 v = ((const float4*)(x + (size_t)row*DIM))[t];
  float s  = v.x + v.y + v.z + v.w;
  float s2 = v.x*v.x + v.y*v.y + v.z*v.z + v.w*v.w;
  #pragma unroll
  for (int d = 32; d >= 1; d >>= 1){ s += __shfl_down(s, d); s2 += __shfl_down(s2, d); }
  __shared__ float ps[2], ps2[2];
  if ((t & 63) == 0){ ps[t >> 6] = s; ps2[t >> 6] = s2; }
  __syncthreads();
  const float mu  = (ps[0] + ps[1]) * (1.f/DIM);
  const float var = (ps2[0] + ps2[1]) * (1.f/DIM) - mu*mu;
  const float rs  = rsqrtf(var + 1e-5f);
  const float4 gm = ((const float4*)g)[t];
  const float4 bt = ((const float4*)b)[t];
  unsigned long long pk =
      (unsigned long long)f2bf((v.x-mu)*rs*gm.x + bt.x)
    | ((unsigned long long)f2bf((v.y-mu)*rs*gm.y + bt.y) << 16)
    | ((unsigned long long)f2bf((v.z-mu)*rs*gm.z + bt.z) << 32)
    | ((unsigned long long)f2bf((v.w-mu)*rs*gm.w + bt.w) << 48);
  *(unsigned long long*)(xn + (size_t)row*DIM + t*4) = pk;
}

// ---------- transpose fp32 W[R][C] -> bf16 WT[C][R] (LDS-tiled) ----------
__global__ __launch_bounds__(256)
void transpose_f32_to_bf16T(const float* __restrict__ W, unsigned short* __restrict__ WT,
                            int R, int C)
{
  __shared__ float tile[32][33];
  const int bc = blockIdx.x*32, br = blockIdx.y*32;
  const int tx = threadIdx.x & 31, ty = threadIdx.x >> 5;  // ty 0..7
  #pragma unroll
  for (int i = 0; i < 32; i += 8) tile[ty+i][tx] = W[(size_t)(br+ty+i)*C + bc+tx];
  __syncthreads();
  #pragma unroll
  for (int i = 0; i < 32; i += 8) WT[(size_t)(bc+ty+i)*R + br+tx] = f2bf(tile[tx][ty+i]);
}

// ---------------- RoPE sin/cos table [2048][64] fp32 ----------------
__global__ __launch_bounds__(256)
void rope_table(float* __restrict__ sin_t, float* __restrict__ cos_t)
{
  const int idx = blockIdx.x*256 + threadIdx.x;     // exactly 2048*64
  const int pos = idx >> 6, i = idx & 63;
  const float freq = expf((float)i * (-9.210340371976184f / 64.f)); // 10000^(-i/64)
  const float ang  = (float)pos * freq;
  sin_t[idx] = sinf(ang);
  cos_t[idx] = cosf(ang);
}

// --------- GEMM: C[M,N] = A[M,K]bf16 * BT[N,K]bf16  (128x128 tile, BK=32) ---------
// LDS slot s (16B) holds (row = s>>2, chunk = (s&3) ^ ((row>>1)&3)) -> frag reads
// (ds_read_b128) conflict-free while global staging stays 64B-coalesced.
template<int OUT_BF16, int ADD_BIAS>
__global__ __launch_bounds__(256)
void gemm128(const unsigned short* __restrict__ A, const unsigned short* __restrict__ BT,
             void* __restrict__ Cout, const float* __restrict__ bias, int M, int N, int K)
{
  __shared__ unsigned short Asm_[128*32];
  __shared__ unsigned short Bsm_[128*32];
  const int t = threadIdx.x;
  const int lane = t & 63, w = t >> 6;
  const int g = lane >> 4, r16 = lane & 15;
  const size_t bm = (size_t)blockIdx.x * 128, bn = (size_t)blockIdx.y * 128;
  const int wm = (w >> 1) * 64, wn = (w & 1) * 64;
  f4_t acc[4][4] = {};

  int aoff[4], boff[4];
  #pragma unroll
  for (int m = 0; m < 4; ++m){
    const int row = wm + m*16 + r16;
    aoff[m] = (row*4 + (g ^ ((row >> 1) & 3))) * 16;
    const int col = wn + m*16 + r16;
    boff[m] = (col*4 + (g ^ ((col >> 1) & 3))) * 16;
  }
  int srow[2], scol[2];
  #pragma unroll
  for (int rd = 0; rd < 2; ++rd){
    const int slot = rd*256 + t;
    srow[rd] = slot >> 2;
    scol[rd] = ((slot & 3) ^ ((srow[rd] >> 1) & 3)) * 8;
  }

  for (int k0 = 0; k0 < K; k0 += 32){
    #pragma unroll
    for (int rd = 0; rd < 2; ++rd){
      const unsigned short* ga = A  + (bm + srow[rd])*K + k0 + scol[rd];
      const unsigned short* gb = BT + (bn + srow[rd])*K + k0 + scol[rd];
      __builtin_amdgcn_global_load_lds((const __attribute__((address_space(1))) void*)ga,
          (__attribute__((address_space(3))) void*)((char*)Asm_ + (rd*256 + w*64)*16), 16, 0, 0);
      __builtin_amdgcn_global_load_lds((const __attribute__((address_space(1))) void*)gb,
          (__attribute__((address_space(3))) void*)((char*)Bsm_ + (rd*256 + w*64)*16), 16, 0, 0);
    }
    __syncthreads();   // compiler drains vmcnt before s_barrier
    bf8_t af[4], bfr[4];
    #pragma unroll
    for (int m = 0; m < 4; ++m) af[m]  = *(const bf8_t*)((const char*)Asm_ + aoff[m]);
    #pragma unroll
    for (int n = 0; n < 4; ++n) bfr[n] = *(const bf8_t*)((const char*)Bsm_ + boff[n]);
    #pragma unroll
    for (int m = 0; m < 4; ++m)
      #pragma unroll
      for (int n = 0; n < 4; ++n)
        acc[m][n] = __builtin_amdgcn_mfma_f32_16x16x32_bf16(af[m], bfr[n], acc[m][n], 0, 0, 0);
    __syncthreads();
  }

  #pragma unroll
  for (int m = 0; m < 4; ++m)
    #pragma unroll
    for (int n = 0; n < 4; ++n)
      #pragma unroll
      for (int r = 0; r < 4; ++r){
        const size_t row = bm + wm + m*16 + g*4 + r;   // D: row=(l>>4)*4+reg
        const size_t col = bn + wn + n*16 + r16;       // D: col=l&15
        float v = acc[m][n][r];
        if (ADD_BIAS) v += bias[col];
        if (OUT_BF16) ((unsigned short*)Cout)[row*N + col] = f2bf(v);
        else          ((float*)Cout)[row*N + col] = v;
      }
}

// ---------- RoPE apply + head relayout: qkv[8192][1536] -> Qh/Kh/Vh [32][2048][64] ----------
__global__ __launch_bounds__(256)
void rope_apply(const unsigned short* __restrict__ qkv, const float* __restrict__ sin_t,
                const float* __restrict__ cos_t, unsigned short* __restrict__ Qh,
                unsigned short* __restrict__ Kh, unsigned short* __restrict__ Vh)
{
  const int wid  = blockIdx.x*4 + (threadIdx.x >> 6);   // one wave per (bh, n)
  const int lane = threadIdx.x & 63;
  const int n  = wid & (N_-1);
  const int bh = wid >> 11;
  const int h = bh & 7, b = bh >> 3;
  const size_t src = ((size_t)(b*N_ + n))*QKVN + h*DH + lane;
  const float q = bf2f(qkv[src]);
  const float k = bf2f(qkv[src + INNER]);
  const unsigned short v = qkv[src + 2*INNER];
  const float qm = __shfl(q, (lane + 63) & 63);   // roll(x,1,-1): elem i-1 (wraps)
  const float km = __shfl(k, (lane + 63) & 63);
  const float sn = sin_t[n*DH + lane], cs = cos_t[n*DH + lane];
  const size_t dst = ((size_t)bh*N_ + n)*DH + lane;
  Qh[dst] = f2bf(q*cs + qm*sn);
  Kh[dst] = f2bf(k*cs + km*sn);
  Vh[dst] = v;
}

// ---------------- flash attention: per (bh), Q-tile 64 rows, K-tiles of 64 ----------------
__global__ __launch_bounds__(256)
void flash_attn(const unsigned short* __restrict__ Qh, const unsigned short* __restrict__ Kh,
                const unsigned short* __restrict__ Vh, unsigned short* __restrict__ Oh)
{
  __shared__ unsigned short Ksm[64*64];     // [key][d], XOR-swizzled rows
  __shared__ unsigned short Vsm[64*64];     // [d][key] (transposed), XOR-swizzled rows
  __shared__ unsigned short Psm[4][16*64];  // per-wave P [q][key], XOR-swizzled
  const int t = threadIdx.x, lane = t & 63, w = t >> 6;
  const int g = lane >> 4, r16 = lane & 15;
  const int bh = blockIdx.y;
  const size_t base = (size_t)bh * (N_*DH);
  const int q0 = blockIdx.x*64 + w*16;

  bf8_t qa[2];  // Q A-frags, 16 rows x 64 dh, held in regs for whole loop
  #pragma unroll
  for (int kc = 0; kc < 2; ++kc)
    qa[kc] = *(const bf8_t*)(Qh + base + (size_t)(q0 + r16)*DH + kc*32 + g*8);

  f4_t oacc[4] = {};
  float mrow[4] = {-1e30f, -1e30f, -1e30f, -1e30f};
  float lrow[4] = {0.f, 0.f, 0.f, 0.f};
  const int srow = t >> 2, sseg = t & 3;

  for (int kt = 0; kt < 32; ++kt){
    __syncthreads();  // previous tile's LDS reads complete
    {   // cooperative stage: K row-major, V transposed; both swizzled byte^=((row&7)<<4)
      const uint4* gk = (const uint4*)(Kh + base + (size_t)(kt*64 + srow)*DH + sseg*16);
      const uint4 k0v = gk[0], k1v = gk[1];
      const int byte0 = srow*128 + sseg*32;
      const int sw = (srow & 7) << 4;
      *(uint4*)((char*)Ksm + ((byte0     ) ^ sw)) = k0v;
      *(uint4*)((char*)Ksm + ((byte0 + 16) ^ sw)) = k1v;
      union { uint4 u[2]; unsigned short s[16]; } vv;
      const uint4* gv = (const uint4*)(Vh + base + (size_t)(kt*64 + srow)*DH + sseg*16);
      vv.u[0] = gv[0]; vv.u[1] = gv[1];
      #pragma unroll
      for (int e = 0; e < 16; ++e){
        const int d = sseg*16 + e;
        *(unsigned short*)((char*)Vsm + ((d*128 + srow*2) ^ ((d & 7) << 4))) = vv.s[e];
      }
    }
    __syncthreads();

    // S = Q K^T (16 q-rows x 64 keys per wave)
    f4_t s[4];
    #pragma unroll
    for (int j = 0; j < 4; ++j){
      const int row = j*16 + r16;
      const int sw = (row & 7) << 4;
      const bf8_t kb0 = *(const bf8_t*)((char*)Ksm + ((row*128      + g*16) ^ sw));
      const bf8_t kb1 = *(const bf8_t*)((char*)Ksm + ((row*128 + 64 + g*16) ^ sw));
      f4_t z = {0.f, 0.f, 0.f, 0.f};
      z = __builtin_amdgcn_mfma_f32_16x16x32_bf16(qa[0], kb0, z, 0, 0, 0);
      z = __builtin_amdgcn_mfma_f32_16x16x32_bf16(qa[1], kb1, z, 0, 0, 0);
      s[j] = z;
    }

    // online softmax; rows = g*4+r, row-reduce over the 16 r16-lanes
    float p[4][4], fscale[4];
    #pragma unroll
    for (int r = 0; r < 4; ++r){
      float mx = fmaxf(fmaxf(s[0][r], s[1][r]), fmaxf(s[2][r], s[3][r]));
      mx = fmaxf(mx, __shfl_xor(mx, 1));
      mx = fmaxf(mx, __shfl_xor(mx, 2));
      mx = fmaxf(mx, __shfl_xor(mx, 4));
      mx = fmaxf(mx, __shfl_xor(mx, 8));
      mx *= 0.125f;
      const float mnew = fmaxf(mrow[r], mx);
      fscale[r] = __expf(mrow[r] - mnew);
      mrow[r] = mnew;
      float ps = 0.f;
      #pragma unroll
      for (int j = 0; j < 4; ++j){ p[j][r] = __expf(s[j][r]*0.125f - mnew); ps += p[j][r]; }
      ps += __shfl_xor(ps, 1); ps += __shfl_xor(ps, 2);
      ps += __shfl_xor(ps, 4); ps += __shfl_xor(ps, 8);
      lrow[r] = lrow[r]*fscale[r] + ps;
    }
    #pragma unroll
    for (int nt = 0; nt < 4; ++nt){
      f4_t o = oacc[nt];
      o[0] *= fscale[0]; o[1] *= fscale[1]; o[2] *= fscale[2]; o[3] *= fscale[3];
      oacc[nt] = o;
    }

    // P -> per-wave LDS (D-layout scatter), then re-read as A-frags
    unsigned short* pw = Psm[w];
    #pragma unroll
    for (int j = 0; j < 4; ++j)
      #pragma unroll
      for (int r = 0; r < 4; ++r){
        const int row = g*4 + r;
        *(unsigned short*)((char*)pw + ((row*128 + (j*16 + r16)*2) ^ ((row & 7) << 4)))
            = f2bf(p[j][r]);
      }
    asm volatile("s_waitcnt lgkmcnt(0)" ::: "memory");  // order write->read (same wave)
    bf8_t pa[2];
    {
      const int row = r16; const int sw = (row & 7) << 4;
      pa[0] = *(const bf8_t*)((char*)pw + ((row*128      + g*16) ^ sw));
      pa[1] = *(const bf8_t*)((char*)pw + ((row*128 + 64 + g*16) ^ sw));
    }
    #pragma unroll
    for (int nt = 0; nt < 4; ++nt){
      const int d = nt*16 + r16; const int sw = (d & 7) << 4;
      const bf8_t vb0 = *(const bf8_t*)((char*)Vsm + ((d*128      + g*16) ^ sw));
      const bf8_t vb1 = *(const bf8_t*)((char*)Vsm + ((d*128 + 64 + g*16) ^ sw));
      oacc[nt] = __builtin_amdgcn_mfma_f32_16x16x32_bf16(pa[0], vb0, oacc[nt], 0, 0, 0);
      oacc[nt] = __builtin_amdgcn_mfma_f32_16x16x32_bf16(pa[1], vb1, oacc[nt], 0, 0, 0);
    }
  }

  // epilogue: O /= l, store [b,n,h*dh] bf16
  const int b = bh >> 3, h = bh & 7;
  #pragma unroll
  for (int nt = 0; nt < 4; ++nt)
    #pragma unroll
    for (int r = 0; r < 4; ++r){
      const int qrow = q0 + g*4 + r;
      Oh[((size_t)(b*N_ + qrow))*INNER + h*DH + nt*16 + r16] = f2bf(oacc[nt][r] / lrow[r]);
    }
}

extern "C" void kernel_launch(void* const* d_in, const int* in_sizes, int n_in,
                              void* d_out, int out_size, void* d_ws, size_t ws_size,
                              hipStream_t stream)
{
  const float* x     = (const float*)d_in[0];
  const float* ln_g  = (const float*)d_in[1];
  const float* ln_b  = (const float*)d_in[2];
  const float* w_qkv = (const float*)d_in[3];  // [512, 1536]
  const float* w_out = (const float*)d_in[4];  // [512, 512]
  const float* b_out = (const float*)d_in[5];
  float* out = (float*)d_out;

  char* ws = (char*)d_ws;
  size_t off = 0;
  auto alloc = [&](size_t bytes) -> void* {
    void* p = ws + off; off += (bytes + 255) & ~(size_t)255; return p;
  };
  float*          sin_t = (float*)alloc((size_t)N_*DH*4);
  float*          cos_t = (float*)alloc((size_t)N_*DH*4);
  unsigned short* wqkvT = (unsigned short*)alloc((size_t)QKVN*DIM*2);   // [1536][512]
  unsigned short* woutT = (unsigned short*)alloc((size_t)DIM*INNER*2);  // [512][512]
  unsigned short* xn    = (unsigned short*)alloc((size_t)ROWS*DIM*2);
  unsigned short* qkv   = (unsigned short*)alloc((size_t)ROWS*QKVN*2);
  unsigned short* Qhb   = (unsigned short*)alloc((size_t)ROWS*INNER*2);
  unsigned short* Khb   = (unsigned short*)alloc((size_t)ROWS*INNER*2);
  unsigned short* Vhb   = (unsigned short*)alloc((size_t)ROWS*INNER*2);
  unsigned short* aout  = xn;  // xn dead after QKV GEMM; reuse for attention output

  hipLaunchKernelGGL(ln_kernel, dim3(ROWS), dim3(128), 0, stream, x, ln_g, ln_b, xn);
  hipLaunchKernelGGL(transpose_f32_to_bf16T, dim3(QKVN/32, DIM/32), dim3(256), 0, stream,
                     w_qkv, wqkvT, DIM, QKVN);
  hipLaunchKernelGGL(transpose_f32_to_bf16T, dim3(DIM/32, INNER/32), dim3(256), 0, stream,
                     w_out, woutT, INNER, DIM);
  hipLaunchKernelGGL(rope_table, dim3((N_*DH)/256), dim3(256), 0, stream, sin_t, cos_t);
  hipLaunchKernelGGL((gemm128<1,0>), dim3(ROWS/128, QKVN/128), dim3(256), 0, stream,
                     xn, wqkvT, (void*)qkv, (const float*)nullptr, ROWS, QKVN, DIM);
  hipLaunchKernelGGL(rope_apply, dim3((ROWS*HEADS)/4), dim3(256), 0, stream,
                     qkv, sin_t, cos_t, Qhb, Khb, Vhb);
  hipLaunchKernelGGL(flash_attn, dim3(N_/64, B_*HEADS), dim3(256), 0, stream,
                     Qhb, Khb, Vhb, aout);
  hipLaunchKernelGGL((gemm128<0,1>), dim3(ROWS/128, DIM/128), dim3(256), 0, stream,
                     aout, woutT, (void*)out, b_out, ROWS, DIM, DIM);
}